// Round 6
// baseline (517.099 us; speedup 1.0000x reference)
//
#include <hip/hip_runtime.h>

// MPNN sparse on MI355X (fp32 I/O, bf16 MFMA compute).
// R6 changes vs R5 (latency/occupancy attack per rocprof):
//  1. sA/sH aliased into one 38KB LDS buffer -> 4 blocks/CU (was 72KB -> 2).
//  2. unsafeAtomicAdd (native global_atomic_add_f32, no CAS loop).
//  3. L1 epilogue: shuffle-pack pairs of columns -> conflict-free b32 LDS
//     writes (was 4-way-conflicted scalar b16).
//  4. __launch_bounds__(256,4) to pin VGPR<=128 (already 128).

#define N_NODES 50000
#define E_EDGES 800000
#define DF   144
#define DIN  128
#define DDEG 16
#define DMSG 128
#define SA_LD 296     // gather-phase row stride (288 + 8 pad), shorts
#define SH_LD 264     // hidden-phase row stride (256 + 8 pad), shorts

typedef __attribute__((ext_vector_type(8))) short short8;   // MFMA A/B frag
typedef __attribute__((ext_vector_type(4))) float floatx4;  // MFMA C/D frag

__device__ __forceinline__ short f2bf(float f){
  union { float f; unsigned int i; } v;
  v.f = f;
  unsigned int r = v.i + 0x7fffu + ((v.i >> 16) & 1u);   // RNE
  return (short)(r >> 16);
}

// ---- sentinel: ws too small -> out = 2.0 (diagnostic) ----
__global__ void sentinel_kernel(float* __restrict__ out){
  int i = blockIdx.x * blockDim.x + threadIdx.x;
  if (i < N_NODES * DMSG){
    out[i] = 2.0f;
  }
}

// ---- init: agg = 0 ----
__global__ void init_kernel(float* __restrict__ agg){
  int i = blockIdx.x * blockDim.x + threadIdx.x;
  if (i < N_NODES * DMSG){
    agg[i] = 0.0f;
  }
}

// ---- h = bf16([x | degrees]) [N x 144] ----
__global__ void build_h_kernel(const float* __restrict__ x, const float* __restrict__ deg,
                               short* __restrict__ h){
  int c = blockIdx.x * blockDim.x + threadIdx.x;     // 18 chunks of 8 per node
  if (c >= N_NODES * 18) return;
  int n = c / 18;
  int j = c - n * 18;
  const float* src;
  if (j < 16){
    src = x + (size_t)n * DIN + (size_t)j * 8;
  } else {
    src = deg + (size_t)n * DDEG + (size_t)(j - 16) * 8;
  }
  short8 v;
  for (int t = 0; t < 8; ++t){
    v[t] = f2bf(src[t]);
  }
  *(short8*)(h + (size_t)n * DF + (size_t)j * 8) = v;
}

// ---- pack fp32 W [Ksrc x (nT*16)] row-major into bf16 MFMA B-fragment order ----
__global__ void pack_w_kernel(const float* __restrict__ W, short* __restrict__ Wp,
                              int Ksrc, int nT){
  int t = blockIdx.x * blockDim.x + threadIdx.x;
  int lane = t & 63;
  int rest = t >> 6;
  int nt = rest % nT;
  int chunk = rest / nT;
  int Ncols = nT * 16;
  int n = nt * 16 + (lane & 15);
  int kbase = chunk * 32 + (lane >> 4) * 8;
  short8 v;
  for (int j = 0; j < 8; ++j){
    int k = kbase + j;
    short o = 0;
    if (k < Ksrc){
      o = f2bf(W[(size_t)k * Ncols + n]);
    }
    v[j] = o;
  }
  *(short8*)(Wp + (size_t)t * 8) = v;
}

// Shared epilogue helper: bias+relu acc[it][jt], pack column-pairs via one
// shfl_xor, write two b32 words (rows r0, r0+1) -> conflict-free LDS.
__device__ __forceinline__ void epilogue_pair_store(short* sBuf, const floatx4& a,
                                                    float bb, int it, int q, int lr,
                                                    int colb){
  float v0 = a[0] + bb; if (v0 < 0.0f) v0 = 0.0f;
  float v1 = a[1] + bb; if (v1 < 0.0f) v1 = 0.0f;
  float v2 = a[2] + bb; if (v2 < 0.0f) v2 = 0.0f;
  float v3 = a[3] + bb; if (v3 < 0.0f) v3 = 0.0f;
  unsigned int c0 = (unsigned short)f2bf(v0);
  unsigned int c1 = (unsigned short)f2bf(v1);
  unsigned int c2 = (unsigned short)f2bf(v2);
  unsigned int c3 = (unsigned short)f2bf(v3);
  unsigned int pk01 = c0 | (c1 << 16);
  unsigned int pk23 = c2 | (c3 << 16);
  unsigned int send = (lr & 1) ? pk01 : pk23;
  unsigned int t = (unsigned int)__shfl_xor((int)send, 1, 64);
  int row0;
  unsigned int w0, w1;
  if ((lr & 1) == 0){
    row0 = it * 16 + q * 4;                       // rows r0, r0+1
    w0 = (pk01 & 0xffffu) | ((t & 0xffffu) << 16);
    w1 = (pk01 >> 16)     | (t & 0xffff0000u);
  } else {
    row0 = it * 16 + q * 4 + 2;                   // rows r0+2, r0+3
    w0 = (t & 0xffffu) | ((pk23 & 0xffffu) << 16);
    w1 = (t >> 16)     | (pk23 & 0xffff0000u);
  }
  *(unsigned int*)(sBuf + row0 * SH_LD + colb) = w0;
  *(unsigned int*)(sBuf + (row0 + 1) * SH_LD + colb) = w1;
}

// ---- edge kernel: 64 edges / block, single aliased LDS buffer ----
__launch_bounds__(256, 4)
__global__ void edge_kernel(const short* __restrict__ h, const int* __restrict__ ei,
                            const short* __restrict__ w1p, const short* __restrict__ w2p,
                            const float* __restrict__ b1, const float* __restrict__ b2,
                            float* __restrict__ agg){
  __shared__ short sBuf[64 * SA_LD];   // gather buf [64x288], then hidden [64x256]
  __shared__ int sT[64];

  const int tid  = threadIdx.x;
  const int lane = tid & 63;
  const int wave = tid >> 6;
  const int q    = lane >> 4;
  const int lr   = lane & 15;
  const int e0   = blockIdx.x * 64;

  // gather: sBuf[e][0:144] = h[tgt[e]], sBuf[e][144:288] = h[src[e]]
  {
    int r    = tid >> 1;          // 0..127
    int half = tid & 1;
    int el   = r & 63;
    int part = r >> 6;            // 0: tgt (h_i), 1: src (h_j)
    int idx;
    if (part){
      idx = ei[e0 + el];              // source j
    } else {
      idx = ei[E_EDGES + e0 + el];    // target i
    }
    if ((unsigned)idx >= (unsigned)N_NODES) idx = 0;
    if (tid < 64){
      int tg = ei[E_EDGES + e0 + tid];
      if ((unsigned)tg >= (unsigned)N_NODES) tg = 0;
      sT[tid] = tg;
    }
    const short* srcp = h + (size_t)idx * DF + half * 72;
    short* dstp = sBuf + el * SA_LD + part * DF + half * 72;
    #pragma unroll
    for (int c = 0; c < 9; ++c){
      *(short8*)(dstp + c * 8) = *(const short8*)(srcp + c * 8);
    }
  }
  __syncthreads();

  // layer 1: [64x288] @ [288x256]
  floatx4 acc[4][4];
  #pragma unroll
  for (int it = 0; it < 4; ++it){
    #pragma unroll
    for (int jt = 0; jt < 4; ++jt){
      #pragma unroll
      for (int r = 0; r < 4; ++r){
        acc[it][jt][r] = 0.0f;
      }
    }
  }

  for (int kc = 0; kc < 9; ++kc){
    short8 aF[4];
    #pragma unroll
    for (int it = 0; it < 4; ++it){
      aF[it] = *(const short8*)(sBuf + (it * 16 + lr) * SA_LD + kc * 32 + q * 8);
    }
    #pragma unroll
    for (int jt = 0; jt < 4; ++jt){
      short8 bF = *(const short8*)(w1p + ((size_t)(kc * 16 + wave * 4 + jt) * 64 + lane) * 8);
      #pragma unroll
      for (int it = 0; it < 4; ++it){
        acc[it][jt] = __builtin_amdgcn_mfma_f32_16x16x32_bf16(aF[it], bF, acc[it][jt], 0, 0, 0);
      }
    }
  }
  __syncthreads();   // all gather-layout reads done before re-striding as hidden

  // epilogue: bias+relu -> sBuf (hidden layout, SH_LD stride), paired b32 writes
  #pragma unroll
  for (int jt = 0; jt < 4; ++jt){
    int col  = wave * 64 + jt * 16 + lr;
    int colb = wave * 64 + jt * 16 + (lr & ~1);
    float bb = b1[col];
    #pragma unroll
    for (int it = 0; it < 4; ++it){
      epilogue_pair_store(sBuf, acc[it][jt], bb, it, q, lr, colb);
    }
  }
  __syncthreads();

  // layer 2: [64x256] @ [256x128] + b2 -> atomic scatter to agg[tgt]
  floatx4 acc2[4][2];
  #pragma unroll
  for (int it = 0; it < 4; ++it){
    #pragma unroll
    for (int jt = 0; jt < 2; ++jt){
      #pragma unroll
      for (int r = 0; r < 4; ++r){
        acc2[it][jt][r] = 0.0f;
      }
    }
  }

  for (int kc = 0; kc < 8; ++kc){
    short8 aF[4];
    #pragma unroll
    for (int it = 0; it < 4; ++it){
      aF[it] = *(const short8*)(sBuf + (it * 16 + lr) * SH_LD + kc * 32 + q * 8);
    }
    #pragma unroll
    for (int jt = 0; jt < 2; ++jt){
      short8 bF = *(const short8*)(w2p + ((size_t)(kc * 8 + wave * 2 + jt) * 64 + lane) * 8);
      #pragma unroll
      for (int it = 0; it < 4; ++it){
        acc2[it][jt] = __builtin_amdgcn_mfma_f32_16x16x32_bf16(aF[it], bF, acc2[it][jt], 0, 0, 0);
      }
    }
  }

  #pragma unroll
  for (int jt = 0; jt < 2; ++jt){
    int col = wave * 32 + jt * 16 + lr;
    float bb = b2[col];
    #pragma unroll
    for (int it = 0; it < 4; ++it){
      #pragma unroll
      for (int r = 0; r < 4; ++r){
        int row = it * 16 + q * 4 + r;
        unsafeAtomicAdd(agg + (size_t)sT[row] * DMSG + col, acc2[it][jt][r] + bb);
      }
    }
  }
}

// ---- node kernel: 64 nodes / block, single aliased LDS buffer ----
__launch_bounds__(256, 4)
__global__ void node_kernel(const short* __restrict__ h, const float* __restrict__ agg,
                            const short* __restrict__ w1p, const short* __restrict__ w2p,
                            const float* __restrict__ b1, const float* __restrict__ b2,
                            float* __restrict__ out){
  __shared__ short sBuf[64 * SA_LD];

  const int tid  = threadIdx.x;
  const int lane = tid & 63;
  const int wave = tid >> 6;
  const int q    = lane >> 4;
  const int lr   = lane & 15;
  const int n0   = blockIdx.x * 64;

  // stage: sBuf[r] = [h[n](144) | bf16(agg[n])(128) | 0(16)]
  if (tid < 128){
    int row = tid >> 1;
    int half = tid & 1;
    int n = n0 + row;
    if (n >= N_NODES) n = 0;
    const short* srcp = h + (size_t)n * DF + half * 72;
    short* dstp = sBuf + row * SA_LD + half * 72;
    #pragma unroll
    for (int c = 0; c < 9; ++c){
      *(short8*)(dstp + c * 8) = *(const short8*)(srcp + c * 8);
    }
  } else {
    int t2 = tid - 128;
    int row = t2 >> 1;
    int half = t2 & 1;
    int n = n0 + row;
    if (n >= N_NODES) n = 0;
    const float* ap = agg + (size_t)n * DMSG + half * 64;
    short* dstp = sBuf + row * SA_LD + DF + half * 64;
    #pragma unroll
    for (int c = 0; c < 64; ++c){
      dstp[c] = f2bf(ap[c]);
    }
    short* padp = sBuf + row * SA_LD + 272 + half * 8;
    #pragma unroll
    for (int t = 0; t < 8; ++t){
      padp[t] = 0;
    }
  }
  __syncthreads();

  // layer 1
  floatx4 acc[4][4];
  #pragma unroll
  for (int it = 0; it < 4; ++it){
    #pragma unroll
    for (int jt = 0; jt < 4; ++jt){
      #pragma unroll
      for (int r = 0; r < 4; ++r){
        acc[it][jt][r] = 0.0f;
      }
    }
  }

  for (int kc = 0; kc < 9; ++kc){
    short8 aF[4];
    #pragma unroll
    for (int it = 0; it < 4; ++it){
      aF[it] = *(const short8*)(sBuf + (it * 16 + lr) * SA_LD + kc * 32 + q * 8);
    }
    #pragma unroll
    for (int jt = 0; jt < 4; ++jt){
      short8 bF = *(const short8*)(w1p + ((size_t)(kc * 16 + wave * 4 + jt) * 64 + lane) * 8);
      #pragma unroll
      for (int it = 0; it < 4; ++it){
        acc[it][jt] = __builtin_amdgcn_mfma_f32_16x16x32_bf16(aF[it], bF, acc[it][jt], 0, 0, 0);
      }
    }
  }
  __syncthreads();

  #pragma unroll
  for (int jt = 0; jt < 4; ++jt){
    int col  = wave * 64 + jt * 16 + lr;
    int colb = wave * 64 + jt * 16 + (lr & ~1);
    float bb = b1[col];
    #pragma unroll
    for (int it = 0; it < 4; ++it){
      epilogue_pair_store(sBuf, acc[it][jt], bb, it, q, lr, colb);
    }
  }
  __syncthreads();

  // layer 2 -> out (fp32)
  floatx4 acc2[4][2];
  #pragma unroll
  for (int it = 0; it < 4; ++it){
    #pragma unroll
    for (int jt = 0; jt < 2; ++jt){
      #pragma unroll
      for (int r = 0; r < 4; ++r){
        acc2[it][jt][r] = 0.0f;
      }
    }
  }

  for (int kc = 0; kc < 8; ++kc){
    short8 aF[4];
    #pragma unroll
    for (int it = 0; it < 4; ++it){
      aF[it] = *(const short8*)(sBuf + (it * 16 + lr) * SH_LD + kc * 32 + q * 8);
    }
    #pragma unroll
    for (int jt = 0; jt < 2; ++jt){
      short8 bF = *(const short8*)(w2p + ((size_t)(kc * 8 + wave * 2 + jt) * 64 + lane) * 8);
      #pragma unroll
      for (int it = 0; it < 4; ++it){
        acc2[it][jt] = __builtin_amdgcn_mfma_f32_16x16x32_bf16(aF[it], bF, acc2[it][jt], 0, 0, 0);
      }
    }
  }

  #pragma unroll
  for (int jt = 0; jt < 2; ++jt){
    int col = wave * 32 + jt * 16 + lr;
    float bb = b2[col];
    #pragma unroll
    for (int it = 0; it < 4; ++it){
      #pragma unroll
      for (int r = 0; r < 4; ++r){
        int n = n0 + it * 16 + q * 4 + r;
        if (n < N_NODES){
          out[(size_t)n * DMSG + col] = acc2[it][jt][r] + bb;
        }
      }
    }
  }
}

extern "C" void kernel_launch(void* const* d_in, const int* in_sizes, int n_in,
                              void* d_out, int out_size, void* d_ws, size_t ws_size,
                              hipStream_t stream){
  const float* x   = (const float*)d_in[0];
  const int*   ei  = (const int*)d_in[1];
  const float* deg = (const float*)d_in[2];
  const float* mW1 = (const float*)d_in[3];
  const float* mb1 = (const float*)d_in[4];
  const float* mW2 = (const float*)d_in[5];
  const float* mb2 = (const float*)d_in[6];
  const float* uW1 = (const float*)d_in[7];
  const float* ub1 = (const float*)d_in[8];
  const float* uW2 = (const float*)d_in[9];
  const float* ub2 = (const float*)d_in[10];

  // workspace layout (~40.5 MB)
  char* ws = (char*)d_ws;
  float* agg = (float*)ws;                                            // 25.6 MB
  size_t off = (size_t)N_NODES * DMSG * 4;
  short* hbuf = (short*)(ws + off); off += (size_t)N_NODES * DF * 2;  // 14.4 MB
  off = (off + 255) & ~(size_t)255;
  short* w1m = (short*)(ws + off); off += (size_t)9 * 16 * 64 * 8 * 2;
  short* w2m = (short*)(ws + off); off += (size_t)8 * 8 * 64 * 8 * 2;
  short* w1u = (short*)(ws + off); off += (size_t)9 * 16 * 64 * 8 * 2;
  short* w2u = (short*)(ws + off); off += (size_t)8 * 8 * 64 * 8 * 2;

  if (ws_size < off){
    sentinel_kernel<<<(N_NODES * DMSG + 255) / 256, 256, 0, stream>>>((float*)d_out);
    return;
  }

  init_kernel<<<(N_NODES * DMSG + 255) / 256, 256, 0, stream>>>(agg);
  build_h_kernel<<<(N_NODES * 18 + 255) / 256, 256, 0, stream>>>(x, deg, hbuf);
  pack_w_kernel<<<36, 256, 0, stream>>>(mW1, w1m, 288, 16);
  pack_w_kernel<<<16, 256, 0, stream>>>(mW2, w2m, 256, 8);
  pack_w_kernel<<<36, 256, 0, stream>>>(uW1, w1u, 272, 16);
  pack_w_kernel<<<16, 256, 0, stream>>>(uW2, w2u, 256, 8);

  edge_kernel<<<E_EDGES / 64, 256, 0, stream>>>(hbuf, ei, w1m, w2m, mb1, mb2, agg);
  node_kernel<<<(N_NODES + 63) / 64, 256, 0, stream>>>(hbuf, agg, w1u, w2u, ub1, ub2,
                                                       (float*)d_out);
}

// Round 7
// 392.147 us; speedup vs baseline: 1.3186x; 1.3186x over previous
//
#include <hip/hip_runtime.h>

// MPNN sparse on MI355X (fp32 I/O, bf16 MFMA compute).
// R7 structure (attacks the measured atomic-scatter wall, 928 MB HBM/dispatch):
//   P' = h@W1[0:144]+b1, Q = h@W1[144:288]  (per-node GEMM, bf16 tables)
//   sort edges by target (hist -> 2-level scan -> scatter)
//   edge2: hidden = relu(P'[tgt]+Q[src]); msg = hidden@W2+b2; segmented sum
//          over sorted targets -> ~6 atomic rows/block instead of 64.
//   node: MLP([h|agg]) -> out   (unchanged, verified)
// Fallback: if ws_size < ~99MB, run the verified R6 path (needs 40.5MB).

#define N_NODES 50000
#define E_EDGES 800000
#define DF   144
#define DIN  128
#define DDEG 16
#define DMSG 128
#define SA_LD 296     // 288 + 8 pad (shorts)
#define SH_LD 264     // 256 + 8 pad (shorts)
#define PQ_LD 512     // P'(256) | Q(256) per node, bf16
#define KA_LD 168     // 160 + 8 pad (pq A staging)
#define MSG_LD 130    // 128 + 2 pad (fp32 msg buffer)
#define NSCAN 50176   // 196 * 256
#define NBLK_SCAN 196

typedef __attribute__((ext_vector_type(8))) short short8;
typedef __attribute__((ext_vector_type(4))) float floatx4;

__device__ __forceinline__ float bf2f(unsigned short u){
  union { unsigned int i; float f; } v;
  v.i = ((unsigned int)u) << 16;
  return v.f;
}
__device__ __forceinline__ short f2bf(float f){
  union { float f; unsigned int i; } v;
  v.f = f;
  unsigned int r = v.i + 0x7fffu + ((v.i >> 16) & 1u);   // RNE
  return (short)(r >> 16);
}

// ---- sentinel: ws too small even for fallback -> out = 2.0 ----
__global__ void sentinel_kernel(float* __restrict__ out){
  int i = blockIdx.x * blockDim.x + threadIdx.x;
  if (i < N_NODES * DMSG){ out[i] = 2.0f; }
}

// ---- init: agg = 0, cnt = 0 ----
__global__ void init_kernel(float* __restrict__ agg, int* __restrict__ cnt){
  int i = blockIdx.x * blockDim.x + threadIdx.x;
  if (i < N_NODES * DMSG){ agg[i] = 0.0f; }
  if (i < NSCAN){ cnt[i] = 0; }
}

// ---- h = bf16([x | degrees]) [N x 144] ----
__global__ void build_h_kernel(const float* __restrict__ x, const float* __restrict__ deg,
                               short* __restrict__ h){
  int c = blockIdx.x * blockDim.x + threadIdx.x;
  if (c >= N_NODES * 18) return;
  int n = c / 18;
  int j = c - n * 18;
  const float* src;
  if (j < 16){ src = x + (size_t)n * DIN + (size_t)j * 8; }
  else       { src = deg + (size_t)n * DDEG + (size_t)(j - 16) * 8; }
  short8 v;
  for (int t = 0; t < 8; ++t){ v[t] = f2bf(src[t]); }
  *(short8*)(h + (size_t)n * DF + (size_t)j * 8) = v;
}

// ---- pack fp32 W [Ksrc x (nT*16)] into bf16 MFMA B-fragment order ----
__global__ void pack_w_kernel(const float* __restrict__ W, short* __restrict__ Wp,
                              int Ksrc, int nT){
  int t = blockIdx.x * blockDim.x + threadIdx.x;
  int lane = t & 63;
  int rest = t >> 6;
  int nt = rest % nT;
  int chunk = rest / nT;
  int Ncols = nT * 16;
  int n = nt * 16 + (lane & 15);
  int kbase = chunk * 32 + (lane >> 4) * 8;
  short8 v;
  for (int j = 0; j < 8; ++j){
    int k = kbase + j;
    short o = 0;
    if (k < Ksrc){ o = f2bf(W[(size_t)k * Ncols + n]); }
    v[j] = o;
  }
  *(short8*)(Wp + (size_t)t * 8) = v;
}

// ---- pack W1 (288x256) into B-frag order for the PQ GEMM: K=144->160, N=512
// B[k][col] = col<256 ? W1[k][col] : W1[144+k][col-256]; zero for k>=144.
__global__ void pack_w1pq_kernel(const float* __restrict__ W1, short* __restrict__ Wp){
  int t = blockIdx.x * blockDim.x + threadIdx.x;   // 5*32*64 = 10240 threads
  int lane = t & 63;
  int rest = t >> 6;
  int nt = rest % 32;
  int chunk = rest / 32;                            // 0..4
  int col = nt * 16 + (lane & 15);                  // 0..511
  int kbase = chunk * 32 + (lane >> 4) * 8;
  short8 v;
  for (int j = 0; j < 8; ++j){
    int k = kbase + j;
    short o = 0;
    if (k < 144){
      float w = (col < 256) ? W1[(size_t)k * 256 + col]
                            : W1[(size_t)(144 + k) * 256 + (col - 256)];
      o = f2bf(w);
    }
    v[j] = o;
  }
  *(short8*)(Wp + (size_t)t * 8) = v;
}

// ---- sort: histogram of targets ----
__global__ void hist_kernel(const int* __restrict__ ei, int* __restrict__ cnt){
  int e = blockIdx.x * blockDim.x + threadIdx.x;
  if (e >= E_EDGES) return;
  int t = ei[E_EDGES + e];
  if ((unsigned)t >= (unsigned)N_NODES) t = 0;
  atomicAdd(cnt + t, 1);
}

// ---- sort: per-256-chunk exclusive scan ----
__global__ void scan1_kernel(const int* __restrict__ cnt, int* __restrict__ off,
                             int* __restrict__ bsum){
  __shared__ int sD[256];
  int t = threadIdx.x;
  int g = blockIdx.x * 256 + t;
  int v = cnt[g];
  sD[t] = v;
  __syncthreads();
  for (int d = 1; d < 256; d <<= 1){
    int x = (t >= d) ? sD[t - d] : 0;
    __syncthreads();
    sD[t] += x;
    __syncthreads();
  }
  off[g] = sD[t] - v;                 // exclusive
  if (t == 255){ bsum[blockIdx.x] = sD[t]; }
}

// ---- sort: scan of block sums (single block) ----
__global__ void scan2_kernel(const int* __restrict__ bsum, int* __restrict__ bsumEx){
  __shared__ int sD[256];
  int t = threadIdx.x;
  int v = (t < NBLK_SCAN) ? bsum[t] : 0;
  sD[t] = v;
  __syncthreads();
  for (int d = 1; d < 256; d <<= 1){
    int x = (t >= d) ? sD[t - d] : 0;
    __syncthreads();
    sD[t] += x;
    __syncthreads();
  }
  bsumEx[t] = sD[t] - v;
}

// ---- sort: add block offsets, duplicate cursor array ----
__global__ void scan3_kernel(const int* __restrict__ bsumEx, int* __restrict__ off,
                             int* __restrict__ off2){
  int g = blockIdx.x * blockDim.x + threadIdx.x;
  if (g >= NSCAN) return;
  int v = off[g] + bsumEx[g >> 8];
  off[g] = v;
  off2[g] = v;
}

// ---- sort: scatter edges into target-sorted order (tgt<<32 | src) ----
__global__ void scatter_kernel(const int* __restrict__ ei, int* __restrict__ off2,
                               long long* __restrict__ es){
  int e = blockIdx.x * blockDim.x + threadIdx.x;
  if (e >= E_EDGES) return;
  int s = ei[e];
  int t = ei[E_EDGES + e];
  if ((unsigned)s >= (unsigned)N_NODES) s = 0;
  if ((unsigned)t >= (unsigned)N_NODES) t = 0;
  int pos = atomicAdd(off2 + t, 1);
  es[pos] = ((long long)t << 32) | (unsigned int)s;
}

// ---- pq: PQ[n][0:256] = h@W1a + b1, PQ[n][256:512] = h@W1b (bf16) ----
__launch_bounds__(256, 2)
__global__ void pq_kernel(const short* __restrict__ h, const short* __restrict__ w1pq,
                          const float* __restrict__ b1, short* __restrict__ PQ){
  __shared__ short sA[64 * KA_LD];
  const int tid  = threadIdx.x;
  const int lane = tid & 63;
  const int wave = tid >> 6;
  const int q    = lane >> 4;
  const int lr   = lane & 15;
  const int n0   = blockIdx.x * 64;

  // stage A: rows n0..n0+63, K cols 0..143 (pad zeros to 160)
  {
    int row = tid >> 2;
    int quarter = tid & 3;
    int n = n0 + row;
    if (n >= N_NODES) n = 0;
    const short* hp = h + (size_t)n * DF;
    short* dstp = sA + row * KA_LD + quarter * 40;
    #pragma unroll
    for (int c5 = 0; c5 < 5; ++c5){
      int col = quarter * 40 + c5 * 8;
      short8 v;
      if (col < DF){
        v = *(const short8*)(hp + col);
      } else {
        for (int j = 0; j < 8; ++j){ v[j] = 0; }
      }
      *(short8*)(dstp + c5 * 8) = v;
    }
  }
  __syncthreads();

  floatx4 acc[4][8];
  #pragma unroll
  for (int it = 0; it < 4; ++it){
    #pragma unroll
    for (int jt = 0; jt < 8; ++jt){
      #pragma unroll
      for (int r = 0; r < 4; ++r){ acc[it][jt][r] = 0.0f; }
    }
  }

  for (int kc = 0; kc < 5; ++kc){
    short8 aF[4];
    #pragma unroll
    for (int it = 0; it < 4; ++it){
      aF[it] = *(const short8*)(sA + (it * 16 + lr) * KA_LD + kc * 32 + q * 8);
    }
    #pragma unroll
    for (int jt = 0; jt < 8; ++jt){
      short8 bF = *(const short8*)(w1pq + ((size_t)(kc * 32 + wave * 8 + jt) * 64 + lane) * 8);
      #pragma unroll
      for (int it = 0; it < 4; ++it){
        acc[it][jt] = __builtin_amdgcn_mfma_f32_16x16x32_bf16(aF[it], bF, acc[it][jt], 0, 0, 0);
      }
    }
  }

  // epilogue: +b1 on P half, pair-pack to global bf16
  #pragma unroll
  for (int jt = 0; jt < 8; ++jt){
    int col  = (wave * 8 + jt) * 16 + lr;
    int colb = (wave * 8 + jt) * 16 + (lr & ~1);
    float bb = (col < 256) ? b1[col] : 0.0f;
    #pragma unroll
    for (int it = 0; it < 4; ++it){
      floatx4 a = acc[it][jt];
      unsigned int c0 = (unsigned short)f2bf(a[0] + bb);
      unsigned int c1 = (unsigned short)f2bf(a[1] + bb);
      unsigned int c2 = (unsigned short)f2bf(a[2] + bb);
      unsigned int c3 = (unsigned short)f2bf(a[3] + bb);
      unsigned int pk01 = c0 | (c1 << 16);
      unsigned int pk23 = c2 | (c3 << 16);
      unsigned int send = (lr & 1) ? pk01 : pk23;
      unsigned int t = (unsigned int)__shfl_xor((int)send, 1, 64);
      int rowbase;
      unsigned int w0, w1;
      if ((lr & 1) == 0){
        rowbase = n0 + it * 16 + q * 4;
        w0 = (pk01 & 0xffffu) | ((t & 0xffffu) << 16);
        w1 = (pk01 >> 16)     | (t & 0xffff0000u);
      } else {
        rowbase = n0 + it * 16 + q * 4 + 2;
        w0 = (t & 0xffffu) | ((pk23 & 0xffffu) << 16);
        w1 = (t >> 16)     | (pk23 & 0xffff0000u);
      }
      if (rowbase < N_NODES){
        *(unsigned int*)(PQ + (size_t)rowbase * PQ_LD + colb) = w0;
      }
      if (rowbase + 1 < N_NODES){
        *(unsigned int*)(PQ + (size_t)(rowbase + 1) * PQ_LD + colb) = w1;
      }
    }
  }
}

// ---- edge2: sorted-edge message GEMM + segmented scatter ----
__launch_bounds__(256, 4)
__global__ void edge2_kernel(const short* __restrict__ PQ, const long long* __restrict__ es,
                             const short* __restrict__ w2p, const float* __restrict__ b2,
                             float* __restrict__ agg){
  __shared__ short sRaw[64 * SH_LD];          // hidden bf16 [64x256+pad] / msg fp32 alias
  __shared__ int sTgt[64];
  short* sIn = sRaw;
  float* sMsg = (float*)sRaw;                 // 64*130*4 = 33280 <= 33792 bytes

  const int tid  = threadIdx.x;
  const int lane = tid & 63;
  const int wave = tid >> 6;
  const int q    = lane >> 4;
  const int lr   = lane & 15;
  const int p0   = blockIdx.x * 64;

  // phase 1: hidden = relu(P'[tgt] + Q[src]) -> sIn bf16
  {
    int p = tid >> 2;
    int quarter = tid & 3;
    long long ll = es[p0 + p];
    int src = (int)(unsigned int)(ll & 0xffffffffLL);
    int tgt = (int)(ll >> 32);
    if (quarter == 0){ sTgt[p] = tgt; }
    const short* Pp = PQ + (size_t)tgt * PQ_LD;
    const short* Qp = PQ + (size_t)src * PQ_LD + 256;
    #pragma unroll
    for (int i = 0; i < 4; ++i){
      int cb = i * 64 + quarter * 16;
      short8 pa = *(const short8*)(Pp + cb);
      short8 pb = *(const short8*)(Pp + cb + 8);
      short8 qa = *(const short8*)(Qp + cb);
      short8 qb = *(const short8*)(Qp + cb + 8);
      short8 oa, ob;
      #pragma unroll
      for (int j = 0; j < 8; ++j){
        float v = bf2f((unsigned short)pa[j]) + bf2f((unsigned short)qa[j]);
        if (v < 0.0f) v = 0.0f;
        oa[j] = f2bf(v);
        float w = bf2f((unsigned short)pb[j]) + bf2f((unsigned short)qb[j]);
        if (w < 0.0f) w = 0.0f;
        ob[j] = f2bf(w);
      }
      *(short8*)(sIn + p * SH_LD + cb) = oa;
      *(short8*)(sIn + p * SH_LD + cb + 8) = ob;
    }
  }
  __syncthreads();

  // phase 2: msg = hidden @ W2  ([64x256]@[256x128])
  floatx4 acc2[4][2];
  #pragma unroll
  for (int it = 0; it < 4; ++it){
    #pragma unroll
    for (int jt = 0; jt < 2; ++jt){
      #pragma unroll
      for (int r = 0; r < 4; ++r){ acc2[it][jt][r] = 0.0f; }
    }
  }

  for (int kc = 0; kc < 8; ++kc){
    short8 aF[4];
    #pragma unroll
    for (int it = 0; it < 4; ++it){
      aF[it] = *(const short8*)(sIn + (it * 16 + lr) * SH_LD + kc * 32 + q * 8);
    }
    #pragma unroll
    for (int jt = 0; jt < 2; ++jt){
      short8 bF = *(const short8*)(w2p + ((size_t)(kc * 8 + wave * 2 + jt) * 64 + lane) * 8);
      #pragma unroll
      for (int it = 0; it < 4; ++it){
        acc2[it][jt] = __builtin_amdgcn_mfma_f32_16x16x32_bf16(aF[it], bF, acc2[it][jt], 0, 0, 0);
      }
    }
  }
  __syncthreads();   // sIn reads done before aliasing as sMsg

  // phase 2b: msg + b2 -> sMsg fp32
  #pragma unroll
  for (int jt = 0; jt < 2; ++jt){
    int col = wave * 32 + jt * 16 + lr;
    float bb = b2[col];
    #pragma unroll
    for (int it = 0; it < 4; ++it){
      #pragma unroll
      for (int r = 0; r < 4; ++r){
        sMsg[(it * 16 + q * 4 + r) * MSG_LD + col] = acc2[it][jt][r] + bb;
      }
    }
  }
  __syncthreads();

  // phase 3: segmented sum over sorted targets, one atomic row per segment
  {
    int col = tid & 127;
    int r0  = (tid >> 7) * 32;
    float a = 0.0f;
    int cur = sTgt[r0];
    for (int r = r0; r < r0 + 32; ++r){
      int t2 = sTgt[r];
      if (t2 != cur){
        unsafeAtomicAdd(agg + (size_t)cur * DMSG + col, a);
        a = 0.0f;
        cur = t2;
      }
      a += sMsg[r * MSG_LD + col];
    }
    unsafeAtomicAdd(agg + (size_t)cur * DMSG + col, a);
  }
}

// ---- R6 fallback edge kernel (verified) ----
__device__ __forceinline__ void epilogue_pair_store(short* sBuf, const floatx4& a,
                                                    float bb, int it, int q, int lr,
                                                    int colb){
  float v0 = a[0] + bb; if (v0 < 0.0f) v0 = 0.0f;
  float v1 = a[1] + bb; if (v1 < 0.0f) v1 = 0.0f;
  float v2 = a[2] + bb; if (v2 < 0.0f) v2 = 0.0f;
  float v3 = a[3] + bb; if (v3 < 0.0f) v3 = 0.0f;
  unsigned int c0 = (unsigned short)f2bf(v0);
  unsigned int c1 = (unsigned short)f2bf(v1);
  unsigned int c2 = (unsigned short)f2bf(v2);
  unsigned int c3 = (unsigned short)f2bf(v3);
  unsigned int pk01 = c0 | (c1 << 16);
  unsigned int pk23 = c2 | (c3 << 16);
  unsigned int send = (lr & 1) ? pk01 : pk23;
  unsigned int t = (unsigned int)__shfl_xor((int)send, 1, 64);
  int row0;
  unsigned int w0, w1;
  if ((lr & 1) == 0){
    row0 = it * 16 + q * 4;
    w0 = (pk01 & 0xffffu) | ((t & 0xffffu) << 16);
    w1 = (pk01 >> 16)     | (t & 0xffff0000u);
  } else {
    row0 = it * 16 + q * 4 + 2;
    w0 = (t & 0xffffu) | ((pk23 & 0xffffu) << 16);
    w1 = (t >> 16)     | (pk23 & 0xffff0000u);
  }
  *(unsigned int*)(sBuf + row0 * SH_LD + colb) = w0;
  *(unsigned int*)(sBuf + (row0 + 1) * SH_LD + colb) = w1;
}

__launch_bounds__(256, 4)
__global__ void edge_kernel(const short* __restrict__ h, const int* __restrict__ ei,
                            const short* __restrict__ w1p, const short* __restrict__ w2p,
                            const float* __restrict__ b1, const float* __restrict__ b2,
                            float* __restrict__ agg){
  __shared__ short sBuf[64 * SA_LD];
  __shared__ int sT[64];
  const int tid  = threadIdx.x;
  const int lane = tid & 63;
  const int wave = tid >> 6;
  const int q    = lane >> 4;
  const int lr   = lane & 15;
  const int e0   = blockIdx.x * 64;
  {
    int r    = tid >> 1;
    int half = tid & 1;
    int el   = r & 63;
    int part = r >> 6;
    int idx = part ? ei[e0 + el] : ei[E_EDGES + e0 + el];
    if ((unsigned)idx >= (unsigned)N_NODES) idx = 0;
    if (tid < 64){
      int tg = ei[E_EDGES + e0 + tid];
      if ((unsigned)tg >= (unsigned)N_NODES) tg = 0;
      sT[tid] = tg;
    }
    const short* srcp = h + (size_t)idx * DF + half * 72;
    short* dstp = sBuf + el * SA_LD + part * DF + half * 72;
    #pragma unroll
    for (int c = 0; c < 9; ++c){
      *(short8*)(dstp + c * 8) = *(const short8*)(srcp + c * 8);
    }
  }
  __syncthreads();
  floatx4 acc[4][4];
  #pragma unroll
  for (int it = 0; it < 4; ++it){
    #pragma unroll
    for (int jt = 0; jt < 4; ++jt){
      #pragma unroll
      for (int r = 0; r < 4; ++r){ acc[it][jt][r] = 0.0f; }
    }
  }
  for (int kc = 0; kc < 9; ++kc){
    short8 aF[4];
    #pragma unroll
    for (int it = 0; it < 4; ++it){
      aF[it] = *(const short8*)(sBuf + (it * 16 + lr) * SA_LD + kc * 32 + q * 8);
    }
    #pragma unroll
    for (int jt = 0; jt < 4; ++jt){
      short8 bF = *(const short8*)(w1p + ((size_t)(kc * 16 + wave * 4 + jt) * 64 + lane) * 8);
      #pragma unroll
      for (int it = 0; it < 4; ++it){
        acc[it][jt] = __builtin_amdgcn_mfma_f32_16x16x32_bf16(aF[it], bF, acc[it][jt], 0, 0, 0);
      }
    }
  }
  __syncthreads();
  #pragma unroll
  for (int jt = 0; jt < 4; ++jt){
    int col  = wave * 64 + jt * 16 + lr;
    int colb = wave * 64 + jt * 16 + (lr & ~1);
    float bb = b1[col];
    #pragma unroll
    for (int it = 0; it < 4; ++it){
      epilogue_pair_store(sBuf, acc[it][jt], bb, it, q, lr, colb);
    }
  }
  __syncthreads();
  floatx4 acc2[4][2];
  #pragma unroll
  for (int it = 0; it < 4; ++it){
    #pragma unroll
    for (int jt = 0; jt < 2; ++jt){
      #pragma unroll
      for (int r = 0; r < 4; ++r){ acc2[it][jt][r] = 0.0f; }
    }
  }
  for (int kc = 0; kc < 8; ++kc){
    short8 aF[4];
    #pragma unroll
    for (int it = 0; it < 4; ++it){
      aF[it] = *(const short8*)(sBuf + (it * 16 + lr) * SH_LD + kc * 32 + q * 8);
    }
    #pragma unroll
    for (int jt = 0; jt < 2; ++jt){
      short8 bF = *(const short8*)(w2p + ((size_t)(kc * 8 + wave * 2 + jt) * 64 + lane) * 8);
      #pragma unroll
      for (int it = 0; it < 4; ++it){
        acc2[it][jt] = __builtin_amdgcn_mfma_f32_16x16x32_bf16(aF[it], bF, acc2[it][jt], 0, 0, 0);
      }
    }
  }
  #pragma unroll
  for (int jt = 0; jt < 2; ++jt){
    int col = wave * 32 + jt * 16 + lr;
    float bb = b2[col];
    #pragma unroll
    for (int it = 0; it < 4; ++it){
      #pragma unroll
      for (int r = 0; r < 4; ++r){
        int row = it * 16 + q * 4 + r;
        unsafeAtomicAdd(agg + (size_t)sT[row] * DMSG + col, acc2[it][jt][r] + bb);
      }
    }
  }
}

// ---- node kernel (verified, unchanged) ----
__launch_bounds__(256, 4)
__global__ void node_kernel(const short* __restrict__ h, const float* __restrict__ agg,
                            const short* __restrict__ w1p, const short* __restrict__ w2p,
                            const float* __restrict__ b1, const float* __restrict__ b2,
                            float* __restrict__ out){
  __shared__ short sBuf[64 * SA_LD];
  const int tid  = threadIdx.x;
  const int lane = tid & 63;
  const int wave = tid >> 6;
  const int q    = lane >> 4;
  const int lr   = lane & 15;
  const int n0   = blockIdx.x * 64;

  if (tid < 128){
    int row = tid >> 1;
    int half = tid & 1;
    int n = n0 + row;
    if (n >= N_NODES) n = 0;
    const short* srcp = h + (size_t)n * DF + half * 72;
    short* dstp = sBuf + row * SA_LD + half * 72;
    #pragma unroll
    for (int c = 0; c < 9; ++c){
      *(short8*)(dstp + c * 8) = *(const short8*)(srcp + c * 8);
    }
  } else {
    int t2 = tid - 128;
    int row = t2 >> 1;
    int half = t2 & 1;
    int n = n0 + row;
    if (n >= N_NODES) n = 0;
    const float* ap = agg + (size_t)n * DMSG + half * 64;
    short* dstp = sBuf + row * SA_LD + DF + half * 64;
    #pragma unroll
    for (int c = 0; c < 64; ++c){ dstp[c] = f2bf(ap[c]); }
    short* padp = sBuf + row * SA_LD + 272 + half * 8;
    #pragma unroll
    for (int t = 0; t < 8; ++t){ padp[t] = 0; }
  }
  __syncthreads();

  floatx4 acc[4][4];
  #pragma unroll
  for (int it = 0; it < 4; ++it){
    #pragma unroll
    for (int jt = 0; jt < 4; ++jt){
      #pragma unroll
      for (int r = 0; r < 4; ++r){ acc[it][jt][r] = 0.0f; }
    }
  }
  for (int kc = 0; kc < 9; ++kc){
    short8 aF[4];
    #pragma unroll
    for (int it = 0; it < 4; ++it){
      aF[it] = *(const short8*)(sBuf + (it * 16 + lr) * SA_LD + kc * 32 + q * 8);
    }
    #pragma unroll
    for (int jt = 0; jt < 4; ++jt){
      short8 bF = *(const short8*)(w1p + ((size_t)(kc * 16 + wave * 4 + jt) * 64 + lane) * 8);
      #pragma unroll
      for (int it = 0; it < 4; ++it){
        acc[it][jt] = __builtin_amdgcn_mfma_f32_16x16x32_bf16(aF[it], bF, acc[it][jt], 0, 0, 0);
      }
    }
  }
  __syncthreads();
  #pragma unroll
  for (int jt = 0; jt < 4; ++jt){
    int col  = wave * 64 + jt * 16 + lr;
    int colb = wave * 64 + jt * 16 + (lr & ~1);
    float bb = b1[col];
    #pragma unroll
    for (int it = 0; it < 4; ++it){
      epilogue_pair_store(sBuf, acc[it][jt], bb, it, q, lr, colb);
    }
  }
  __syncthreads();
  floatx4 acc2[4][2];
  #pragma unroll
  for (int it = 0; it < 4; ++it){
    #pragma unroll
    for (int jt = 0; jt < 2; ++jt){
      #pragma unroll
      for (int r = 0; r < 4; ++r){ acc2[it][jt][r] = 0.0f; }
    }
  }
  for (int kc = 0; kc < 8; ++kc){
    short8 aF[4];
    #pragma unroll
    for (int it = 0; it < 4; ++it){
      aF[it] = *(const short8*)(sBuf + (it * 16 + lr) * SH_LD + kc * 32 + q * 8);
    }
    #pragma unroll
    for (int jt = 0; jt < 2; ++jt){
      short8 bF = *(const short8*)(w2p + ((size_t)(kc * 8 + wave * 2 + jt) * 64 + lane) * 8);
      #pragma unroll
      for (int it = 0; it < 4; ++it){
        acc2[it][jt] = __builtin_amdgcn_mfma_f32_16x16x32_bf16(aF[it], bF, acc2[it][jt], 0, 0, 0);
      }
    }
  }
  #pragma unroll
  for (int jt = 0; jt < 2; ++jt){
    int col = wave * 32 + jt * 16 + lr;
    float bb = b2[col];
    #pragma unroll
    for (int it = 0; it < 4; ++it){
      #pragma unroll
      for (int r = 0; r < 4; ++r){
        int n = n0 + it * 16 + q * 4 + r;
        if (n < N_NODES){
          out[(size_t)n * DMSG + col] = acc2[it][jt][r] + bb;
        }
      }
    }
  }
}

extern "C" void kernel_launch(void* const* d_in, const int* in_sizes, int n_in,
                              void* d_out, int out_size, void* d_ws, size_t ws_size,
                              hipStream_t stream){
  const float* x   = (const float*)d_in[0];
  const int*   ei  = (const int*)d_in[1];
  const float* deg = (const float*)d_in[2];
  const float* mW1 = (const float*)d_in[3];
  const float* mb1 = (const float*)d_in[4];
  const float* mW2 = (const float*)d_in[5];
  const float* mb2 = (const float*)d_in[6];
  const float* uW1 = (const float*)d_in[7];
  const float* ub1 = (const float*)d_in[8];
  const float* uW2 = (const float*)d_in[9];
  const float* ub2 = (const float*)d_in[10];

  char* ws = (char*)d_ws;
  size_t off = 0;
  float* agg = (float*)(ws + off); off += (size_t)N_NODES * DMSG * 4;       // 25.6 MB
  short* hbuf = (short*)(ws + off); off += (size_t)N_NODES * DF * 2;        // 14.4 MB
  off = (off + 255) & ~(size_t)255;
  short* w2m = (short*)(ws + off); off += (size_t)8 * 8 * 64 * 8 * 2;
  short* w1u = (short*)(ws + off); off += (size_t)9 * 16 * 64 * 8 * 2;
  short* w2u = (short*)(ws + off); off += (size_t)8 * 8 * 64 * 8 * 2;
  short* w1m = (short*)(ws + off); off += (size_t)9 * 16 * 64 * 8 * 2;      // fallback
  size_t need_old = off;
  // new-path extras
  short* PQ = (short*)(ws + off); off += (size_t)N_NODES * PQ_LD * 2;       // 51.2 MB
  long long* es = (long long*)(ws + off); off += (size_t)E_EDGES * 8;       // 6.4 MB
  int* cnt    = (int*)(ws + off); off += (size_t)NSCAN * 4;
  int* offA   = (int*)(ws + off); off += (size_t)NSCAN * 4;
  int* offB   = (int*)(ws + off); off += (size_t)NSCAN * 4;
  int* bsum   = (int*)(ws + off); off += 256 * 4;
  int* bsumEx = (int*)(ws + off); off += 256 * 4;
  short* w1pq = (short*)(ws + off); off += (size_t)5 * 32 * 64 * 8 * 2;
  size_t need_new = off;

  if (ws_size < need_old){
    sentinel_kernel<<<(N_NODES * DMSG + 255) / 256, 256, 0, stream>>>((float*)d_out);
    return;
  }

  init_kernel<<<(N_NODES * DMSG + 255) / 256, 256, 0, stream>>>(agg, cnt);
  build_h_kernel<<<(N_NODES * 18 + 255) / 256, 256, 0, stream>>>(x, deg, hbuf);
  pack_w_kernel<<<16, 256, 0, stream>>>(mW2, w2m, 256, 8);
  pack_w_kernel<<<36, 256, 0, stream>>>(uW1, w1u, 272, 16);
  pack_w_kernel<<<16, 256, 0, stream>>>(uW2, w2u, 256, 8);

  if (ws_size >= need_new){
    pack_w1pq_kernel<<<40, 256, 0, stream>>>(mW1, w1pq);
    pq_kernel<<<(N_NODES + 63) / 64, 256, 0, stream>>>(hbuf, w1pq, mb1, PQ);
    hist_kernel<<<(E_EDGES + 255) / 256, 256, 0, stream>>>(ei, cnt);
    scan1_kernel<<<NBLK_SCAN, 256, 0, stream>>>(cnt, offA, bsum);
    scan2_kernel<<<1, 256, 0, stream>>>(bsum, bsumEx);
    scan3_kernel<<<NBLK_SCAN, 256, 0, stream>>>(bsumEx, offA, offB);
    scatter_kernel<<<(E_EDGES + 255) / 256, 256, 0, stream>>>(ei, offB, es);
    edge2_kernel<<<E_EDGES / 64, 256, 0, stream>>>(PQ, es, w2m, mb2, agg);
  } else {
    pack_w_kernel<<<36, 256, 0, stream>>>(mW1, w1m, 288, 16);
    edge_kernel<<<E_EDGES / 64, 256, 0, stream>>>(hbuf, ei, w1m, w2m, mb1, mb2, agg);
  }

  node_kernel<<<(N_NODES + 63) / 64, 256, 0, stream>>>(hbuf, agg, w1u, w2u, ub1, ub2,
                                                       (float*)d_out);
}

// Round 8
// 344.090 us; speedup vs baseline: 1.5028x; 1.1397x over previous
//
#include <hip/hip_runtime.h>

// MPNN sparse on MI355X (fp32 I/O, bf16 MFMA compute).
// R8: VALU + launch-count attack on the R7 structure.
//  - packed bf16 pair math everywhere (uint32 lanes, v_perm_b32 trunc-pack):
//    edge2 phase-1 (P'+Q relu), pq epilogue, node agg->bf16 staging.
//  - 13 -> 7 kernels: prep(init+build_h), pack+hist, scan1, scan2,
//    pq+scatter (fused, disjoint block ranges), edge2, node. scan3 deleted
//    (scatter adds bsumEx on the fly), es entries 8B -> 4B (ids < 2^16).

#define N_NODES 50000
#define E_EDGES 800000
#define DF   144
#define DIN  128
#define DDEG 16
#define DMSG 128
#define SA_LD 296     // 288 + 8 pad (shorts)
#define SH_LD 264     // 256 + 8 pad (shorts) = 132 uints
#define PQ_LD 512     // P'(256) | Q(256) per node, bf16
#define KA_LD 168     // 160 + 8 pad (pq A staging)
#define MSG_LD 130    // 128 + 2 pad (fp32 msg buffer)
#define NSCAN 50176   // 196 * 256
#define NBLK_SCAN 196
#define PQ_BLOCKS 782     // ceil(50000/64)
#define HIST_BLOCKS 3125  // 800000/256
#define PACK_THREADS 27648

typedef __attribute__((ext_vector_type(8))) short short8;
typedef __attribute__((ext_vector_type(4))) float floatx4;

__device__ __forceinline__ unsigned int fasu(float f){
  union { float f; unsigned int u; } v; v.f = f; return v.u;
}
__device__ __forceinline__ float uasf(unsigned int u){
  union { unsigned int u; float f; } v; v.u = u; return v.f;
}
__device__ __forceinline__ short f2bf(float f){           // RNE (input conversion)
  unsigned int i = fasu(f);
  unsigned int r = i + 0x7fffu + ((i >> 16) & 1u);
  return (short)(r >> 16);
}
// pack two fp32 into two bf16 (truncation) in ONE v_perm_b32
__device__ __forceinline__ unsigned int pk_trunc(float lo, float hi){
  return __builtin_amdgcn_perm(fasu(hi), fasu(lo), 0x07060302u);
}
// (bf16pair u) + (bf16pair v), relu, repack
__device__ __forceinline__ unsigned int addrelu_pk(unsigned int u, unsigned int v){
  float lo = uasf(u << 16) + uasf(v << 16);
  float hi = uasf(u & 0xffff0000u) + uasf(v & 0xffff0000u);
  lo = lo > 0.0f ? lo : 0.0f;
  hi = hi > 0.0f ? hi : 0.0f;
  return pk_trunc(lo, hi);
}

// ---- sentinel: ws too small -> out = 2.0 (diagnostic) ----
__global__ void sentinel_kernel(float* __restrict__ out){
  int i = blockIdx.x * blockDim.x + threadIdx.x;
  if (i < N_NODES * DMSG){ out[i] = 2.0f; }
}

// ---- prep: agg=0, cnt=0, h = bf16([x|deg]) ----
__global__ void prep_kernel(const float* __restrict__ x, const float* __restrict__ deg,
                            float* __restrict__ agg, int* __restrict__ cnt,
                            short* __restrict__ h){
  int i = blockIdx.x * blockDim.x + threadIdx.x;
  if (i < N_NODES * DMSG){ agg[i] = 0.0f; }
  if (i < NSCAN){ cnt[i] = 0; }
  if (i < N_NODES * 18){
    int n = i / 18;
    int j = i - n * 18;
    const float* src;
    if (j < 16){ src = x + (size_t)n * DIN + (size_t)j * 8; }
    else       { src = deg + (size_t)n * DDEG + (size_t)(j - 16) * 8; }
    short8 v;
    for (int t = 0; t < 8; ++t){ v[t] = f2bf(src[t]); }
    *(short8*)(h + (size_t)n * DF + (size_t)j * 8) = v;
  }
}

// ---- pack helpers (device) ----
__device__ __forceinline__ void pack_w_dev(const float* __restrict__ W,
                                           short* __restrict__ Wp,
                                           int Ksrc, int nT, int t){
  int lane = t & 63;
  int rest = t >> 6;
  int nt = rest % nT;
  int chunk = rest / nT;
  int Ncols = nT * 16;
  int n = nt * 16 + (lane & 15);
  int kbase = chunk * 32 + (lane >> 4) * 8;
  short8 v;
  for (int j = 0; j < 8; ++j){
    int k = kbase + j;
    short o = 0;
    if (k < Ksrc){ o = f2bf(W[(size_t)k * Ncols + n]); }
    v[j] = o;
  }
  *(short8*)(Wp + (size_t)t * 8) = v;
}
__device__ __forceinline__ void pack_w1pq_dev(const float* __restrict__ W1,
                                              short* __restrict__ Wp, int t){
  int lane = t & 63;
  int rest = t >> 6;
  int nt = rest % 32;
  int chunk = rest / 32;                 // 0..4
  int col = nt * 16 + (lane & 15);       // 0..511
  int kbase = chunk * 32 + (lane >> 4) * 8;
  short8 v;
  for (int j = 0; j < 8; ++j){
    int k = kbase + j;
    short o = 0;
    if (k < 144){
      float w = (col < 256) ? W1[(size_t)k * 256 + col]
                            : W1[(size_t)(144 + k) * 256 + (col - 256)];
      o = f2bf(w);
    }
    v[j] = o;
  }
  *(short8*)(Wp + (size_t)t * 8) = v;
}

// ---- pack all weights + target histogram (fused) ----
__global__ void pack_hist_kernel(const float* __restrict__ mW1, const float* __restrict__ mW2,
                                 const float* __restrict__ uW1, const float* __restrict__ uW2,
                                 short* __restrict__ w1pq, short* __restrict__ w2m,
                                 short* __restrict__ w1u, short* __restrict__ w2u,
                                 const int* __restrict__ ei, int* __restrict__ cnt){
  int t = blockIdx.x * blockDim.x + threadIdx.x;
  if (t < E_EDGES){
    int tg = ei[E_EDGES + t];
    if ((unsigned)tg >= (unsigned)N_NODES) tg = 0;
    atomicAdd(cnt + tg, 1);
    return;
  }
  int t2 = t - E_EDGES;
  if (t2 >= PACK_THREADS) return;
  if (t2 < 4096){ pack_w_dev(mW2, w2m, 256, 8, t2); }
  else if (t2 < 13312){ pack_w_dev(uW1, w1u, 272, 16, t2 - 4096); }
  else if (t2 < 17408){ pack_w_dev(uW2, w2u, 256, 8, t2 - 13312); }
  else { pack_w1pq_dev(mW1, w1pq, t2 - 17408); }
}

// ---- scan1: per-256-chunk exclusive scan ----
__global__ void scan1_kernel(const int* __restrict__ cnt, int* __restrict__ off,
                             int* __restrict__ bsum){
  __shared__ int sD[256];
  int t = threadIdx.x;
  int g = blockIdx.x * 256 + t;
  int v = cnt[g];
  sD[t] = v;
  __syncthreads();
  for (int d = 1; d < 256; d <<= 1){
    int x2 = (t >= d) ? sD[t - d] : 0;
    __syncthreads();
    sD[t] += x2;
    __syncthreads();
  }
  off[g] = sD[t] - v;
  if (t == 255){ bsum[blockIdx.x] = sD[t]; }
}

// ---- scan2: block sums (single block) ----
__global__ void scan2_kernel(const int* __restrict__ bsum, int* __restrict__ bsumEx){
  __shared__ int sD[256];
  int t = threadIdx.x;
  int v = (t < NBLK_SCAN) ? bsum[t] : 0;
  sD[t] = v;
  __syncthreads();
  for (int d = 1; d < 256; d <<= 1){
    int x2 = (t >= d) ? sD[t - d] : 0;
    __syncthreads();
    sD[t] += x2;
    __syncthreads();
  }
  bsumEx[t] = sD[t] - v;
}

// ---- fused: PQ GEMM (blocks [0,PQ_BLOCKS)) + edge scatter (rest) ----
__launch_bounds__(256, 2)
__global__ void pq_scatter_kernel(const short* __restrict__ h, const short* __restrict__ w1pq,
                                  const float* __restrict__ b1, short* __restrict__ PQ,
                                  const int* __restrict__ ei, int* __restrict__ offA,
                                  const int* __restrict__ bsumEx, unsigned int* __restrict__ es){
  __shared__ short sA[64 * KA_LD];

  if (blockIdx.x >= PQ_BLOCKS){
    int e = (blockIdx.x - PQ_BLOCKS) * 256 + threadIdx.x;
    if (e < E_EDGES){
      int s = ei[e];
      int t = ei[E_EDGES + e];
      if ((unsigned)s >= (unsigned)N_NODES) s = 0;
      if ((unsigned)t >= (unsigned)N_NODES) t = 0;
      int pos = atomicAdd(offA + t, 1) + bsumEx[t >> 8];
      es[pos] = ((unsigned int)t << 16) | (unsigned int)s;
    }
    return;
  }

  const int tid  = threadIdx.x;
  const int lane = tid & 63;
  const int wave = tid >> 6;
  const int q    = lane >> 4;
  const int lr   = lane & 15;
  const int n0   = blockIdx.x * 64;

  // stage A: rows n0..n0+63, K 0..143 (zero-pad to 160)
  {
    int row = tid >> 2;
    int quarter = tid & 3;
    int n = n0 + row;
    if (n >= N_NODES) n = 0;
    const short* hp = h + (size_t)n * DF;
    short* dstp = sA + row * KA_LD + quarter * 40;
    #pragma unroll
    for (int c5 = 0; c5 < 5; ++c5){
      int col = quarter * 40 + c5 * 8;
      short8 v;
      if (col < DF){
        v = *(const short8*)(hp + col);
      } else {
        for (int j = 0; j < 8; ++j){ v[j] = 0; }
      }
      *(short8*)(dstp + c5 * 8) = v;
    }
  }
  __syncthreads();

  floatx4 acc[4][8];
  #pragma unroll
  for (int it = 0; it < 4; ++it){
    #pragma unroll
    for (int jt = 0; jt < 8; ++jt){
      #pragma unroll
      for (int r = 0; r < 4; ++r){ acc[it][jt][r] = 0.0f; }
    }
  }

  for (int kc = 0; kc < 5; ++kc){
    short8 aF[4];
    #pragma unroll
    for (int it = 0; it < 4; ++it){
      aF[it] = *(const short8*)(sA + (it * 16 + lr) * KA_LD + kc * 32 + q * 8);
    }
    #pragma unroll
    for (int jt = 0; jt < 8; ++jt){
      short8 bF = *(const short8*)(w1pq + ((size_t)(kc * 32 + wave * 8 + jt) * 64 + lane) * 8);
      #pragma unroll
      for (int it = 0; it < 4; ++it){
        acc[it][jt] = __builtin_amdgcn_mfma_f32_16x16x32_bf16(aF[it], bF, acc[it][jt], 0, 0, 0);
      }
    }
  }

  // epilogue: +b1 on P half, trunc-pack pairs, shfl-exchange, b32 global stores
  #pragma unroll
  for (int jt = 0; jt < 8; ++jt){
    int col  = (wave * 8 + jt) * 16 + lr;
    int colb = (wave * 8 + jt) * 16 + (lr & ~1);
    float bb = (col < 256) ? b1[col] : 0.0f;
    #pragma unroll
    for (int it = 0; it < 4; ++it){
      floatx4 a = acc[it][jt];
      unsigned int pk01 = pk_trunc(a[0] + bb, a[1] + bb);
      unsigned int pk23 = pk_trunc(a[2] + bb, a[3] + bb);
      unsigned int send = (lr & 1) ? pk01 : pk23;
      unsigned int t = (unsigned int)__shfl_xor((int)send, 1, 64);
      int rowbase;
      unsigned int w0, w1;
      if ((lr & 1) == 0){
        rowbase = n0 + it * 16 + q * 4;
        w0 = (pk01 & 0xffffu) | ((t & 0xffffu) << 16);
        w1 = (pk01 >> 16)     | (t & 0xffff0000u);
      } else {
        rowbase = n0 + it * 16 + q * 4 + 2;
        w0 = (t & 0xffffu) | ((pk23 & 0xffffu) << 16);
        w1 = (t >> 16)     | (pk23 & 0xffff0000u);
      }
      if (rowbase < N_NODES){
        *(unsigned int*)(PQ + (size_t)rowbase * PQ_LD + colb) = w0;
      }
      if (rowbase + 1 < N_NODES){
        *(unsigned int*)(PQ + (size_t)(rowbase + 1) * PQ_LD + colb) = w1;
      }
    }
  }
}

// ---- edge2: hidden = relu(P'[tgt]+Q[src]); msg = hidden@W2+b2; segmented sum ----
__launch_bounds__(256, 4)
__global__ void edge2_kernel(const short* __restrict__ PQ, const unsigned int* __restrict__ es,
                             const short* __restrict__ w2p, const float* __restrict__ b2,
                             float* __restrict__ agg){
  __shared__ __align__(16) short sRaw[64 * SH_LD];
  __shared__ int sTgt[64];
  short* sIn = sRaw;
  float* sMsg = (float*)sRaw;

  const int tid  = threadIdx.x;
  const int lane = tid & 63;
  const int wave = tid >> 6;
  const int q    = lane >> 4;
  const int lr   = lane & 15;
  const int p0   = blockIdx.x * 64;

  // phase 1: packed-pair add+relu, 1 perm/pair
  {
    int p = tid >> 2;
    int quarter = tid & 3;
    unsigned int e = es[p0 + p];
    int src = (int)(e & 0xffffu);
    int tgt = (int)(e >> 16);
    if (quarter == 0){ sTgt[p] = tgt; }
    const unsigned int* Pp = (const unsigned int*)PQ + (size_t)tgt * 256;
    const unsigned int* Qp = (const unsigned int*)PQ + (size_t)src * 256 + 128;
    unsigned int* sRow = (unsigned int*)(sIn + p * SH_LD);
    #pragma unroll
    for (int i = 0; i < 4; ++i){
      int ub = i * 32 + quarter * 8;
      uint4 pa = *(const uint4*)(Pp + ub);
      uint4 pb = *(const uint4*)(Pp + ub + 4);
      uint4 qa = *(const uint4*)(Qp + ub);
      uint4 qb = *(const uint4*)(Qp + ub + 4);
      uint4 oa, ob;
      oa.x = addrelu_pk(pa.x, qa.x);
      oa.y = addrelu_pk(pa.y, qa.y);
      oa.z = addrelu_pk(pa.z, qa.z);
      oa.w = addrelu_pk(pa.w, qa.w);
      ob.x = addrelu_pk(pb.x, qb.x);
      ob.y = addrelu_pk(pb.y, qb.y);
      ob.z = addrelu_pk(pb.z, qb.z);
      ob.w = addrelu_pk(pb.w, qb.w);
      *(uint4*)(sRow + ub) = oa;
      *(uint4*)(sRow + ub + 4) = ob;
    }
  }
  __syncthreads();

  // phase 2: msg = hidden @ W2
  floatx4 acc2[4][2];
  #pragma unroll
  for (int it = 0; it < 4; ++it){
    #pragma unroll
    for (int jt = 0; jt < 2; ++jt){
      #pragma unroll
      for (int r = 0; r < 4; ++r){ acc2[it][jt][r] = 0.0f; }
    }
  }

  for (int kc = 0; kc < 8; ++kc){
    short8 aF[4];
    #pragma unroll
    for (int it = 0; it < 4; ++it){
      aF[it] = *(const short8*)(sIn + (it * 16 + lr) * SH_LD + kc * 32 + q * 8);
    }
    #pragma unroll
    for (int jt = 0; jt < 2; ++jt){
      short8 bF = *(const short8*)(w2p + ((size_t)(kc * 8 + wave * 2 + jt) * 64 + lane) * 8);
      #pragma unroll
      for (int it = 0; it < 4; ++it){
        acc2[it][jt] = __builtin_amdgcn_mfma_f32_16x16x32_bf16(aF[it], bF, acc2[it][jt], 0, 0, 0);
      }
    }
  }
  __syncthreads();

  // phase 2b: +b2 -> sMsg fp32
  #pragma unroll
  for (int jt = 0; jt < 2; ++jt){
    int col = wave * 32 + jt * 16 + lr;
    float bb = b2[col];
    #pragma unroll
    for (int it = 0; it < 4; ++it){
      #pragma unroll
      for (int r = 0; r < 4; ++r){
        sMsg[(it * 16 + q * 4 + r) * MSG_LD + col] = acc2[it][jt][r] + bb;
      }
    }
  }
  __syncthreads();

  // phase 3: segmented sum over sorted targets
  {
    int col = tid & 127;
    int r0  = (tid >> 7) * 32;
    float a = 0.0f;
    int cur = sTgt[r0];
    for (int r = r0; r < r0 + 32; ++r){
      int t2 = sTgt[r];
      if (t2 != cur){
        unsafeAtomicAdd(agg + (size_t)cur * DMSG + col, a);
        a = 0.0f;
        cur = t2;
      }
      a += sMsg[r * MSG_LD + col];
    }
    unsafeAtomicAdd(agg + (size_t)cur * DMSG + col, a);
  }
}

// ---- node kernel ----
__launch_bounds__(256, 4)
__global__ void node_kernel(const short* __restrict__ h, const float* __restrict__ agg,
                            const short* __restrict__ w1p, const short* __restrict__ w2p,
                            const float* __restrict__ b1, const float* __restrict__ b2,
                            float* __restrict__ out){
  __shared__ __align__(16) short sBuf[64 * SA_LD];
  const int tid  = threadIdx.x;
  const int lane = tid & 63;
  const int wave = tid >> 6;
  const int q    = lane >> 4;
  const int lr   = lane & 15;
  const int n0   = blockIdx.x * 64;

  if (tid < 128){
    int row = tid >> 1;
    int half = tid & 1;
    int n = n0 + row;
    if (n >= N_NODES) n = 0;
    const short* srcp = h + (size_t)n * DF + half * 72;
    short* dstp = sBuf + row * SA_LD + half * 72;
    #pragma unroll
    for (int c = 0; c < 9; ++c){
      *(short8*)(dstp + c * 8) = *(const short8*)(srcp + c * 8);
    }
  } else {
    int t2 = tid - 128;
    int row = t2 >> 1;
    int half = t2 & 1;
    int n = n0 + row;
    if (n >= N_NODES) n = 0;
    const float* ap = agg + (size_t)n * DMSG + half * 64;
    unsigned int* dstp = (unsigned int*)(sBuf + row * SA_LD + DF + half * 64);
    #pragma unroll
    for (int c = 0; c < 16; ++c){
      float4 f = *(const float4*)(ap + c * 4);
      dstp[c * 2]     = pk_trunc(f.x, f.y);
      dstp[c * 2 + 1] = pk_trunc(f.z, f.w);
    }
    short* padp = sBuf + row * SA_LD + 272 + half * 8;
    #pragma unroll
    for (int t = 0; t < 8; ++t){ padp[t] = 0; }
  }
  __syncthreads();

  floatx4 acc[4][4];
  #pragma unroll
  for (int it = 0; it < 4; ++it){
    #pragma unroll
    for (int jt = 0; jt < 4; ++jt){
      #pragma unroll
      for (int r = 0; r < 4; ++r){ acc[it][jt][r] = 0.0f; }
    }
  }
  for (int kc = 0; kc < 9; ++kc){
    short8 aF[4];
    #pragma unroll
    for (int it = 0; it < 4; ++it){
      aF[it] = *(const short8*)(sBuf + (it * 16 + lr) * SA_LD + kc * 32 + q * 8);
    }
    #pragma unroll
    for (int jt = 0; jt < 4; ++jt){
      short8 bF = *(const short8*)(w1p + ((size_t)(kc * 16 + wave * 4 + jt) * 64 + lane) * 8);
      #pragma unroll
      for (int it = 0; it < 4; ++it){
        acc[it][jt] = __builtin_amdgcn_mfma_f32_16x16x32_bf16(aF[it], bF, acc[it][jt], 0, 0, 0);
      }
    }
  }
  __syncthreads();

  // epilogue: bias+relu, trunc-pack pairs, shfl-exchange, b32 LDS writes
  #pragma unroll
  for (int jt = 0; jt < 4; ++jt){
    int col  = wave * 64 + jt * 16 + lr;
    int colb = wave * 64 + jt * 16 + (lr & ~1);
    float bb = b1[col];
    #pragma unroll
    for (int it = 0; it < 4; ++it){
      floatx4 a = acc[it][jt];
      float v0 = a[0] + bb; v0 = v0 > 0.0f ? v0 : 0.0f;
      float v1 = a[1] + bb; v1 = v1 > 0.0f ? v1 : 0.0f;
      float v2 = a[2] + bb; v2 = v2 > 0.0f ? v2 : 0.0f;
      float v3 = a[3] + bb; v3 = v3 > 0.0f ? v3 : 0.0f;
      unsigned int pk01 = pk_trunc(v0, v1);
      unsigned int pk23 = pk_trunc(v2, v3);
      unsigned int send = (lr & 1) ? pk01 : pk23;
      unsigned int t = (unsigned int)__shfl_xor((int)send, 1, 64);
      int row0;
      unsigned int w0, w1;
      if ((lr & 1) == 0){
        row0 = it * 16 + q * 4;
        w0 = (pk01 & 0xffffu) | ((t & 0xffffu) << 16);
        w1 = (pk01 >> 16)     | (t & 0xffff0000u);
      } else {
        row0 = it * 16 + q * 4 + 2;
        w0 = (t & 0xffffu) | ((pk23 & 0xffffu) << 16);
        w1 = (t >> 16)     | (pk23 & 0xffff0000u);
      }
      *(unsigned int*)(sBuf + row0 * SH_LD + colb) = w0;
      *(unsigned int*)(sBuf + (row0 + 1) * SH_LD + colb) = w1;
    }
  }
  __syncthreads();

  floatx4 acc2[4][2];
  #pragma unroll
  for (int it = 0; it < 4; ++it){
    #pragma unroll
    for (int jt = 0; jt < 2; ++jt){
      #pragma unroll
      for (int r = 0; r < 4; ++r){ acc2[it][jt][r] = 0.0f; }
    }
  }
  for (int kc = 0; kc < 8; ++kc){
    short8 aF[4];
    #pragma unroll
    for (int it = 0; it < 4; ++it){
      aF[it] = *(const short8*)(sBuf + (it * 16 + lr) * SH_LD + kc * 32 + q * 8);
    }
    #pragma unroll
    for (int jt = 0; jt < 2; ++jt){
      short8 bF = *(const short8*)(w2p + ((size_t)(kc * 8 + wave * 2 + jt) * 64 + lane) * 8);
      #pragma unroll
      for (int it = 0; it < 4; ++it){
        acc2[it][jt] = __builtin_amdgcn_mfma_f32_16x16x32_bf16(aF[it], bF, acc2[it][jt], 0, 0, 0);
      }
    }
  }
  #pragma unroll
  for (int jt = 0; jt < 2; ++jt){
    int col = wave * 32 + jt * 16 + lr;
    float bb = b2[col];
    #pragma unroll
    for (int it = 0; it < 4; ++it){
      #pragma unroll
      for (int r = 0; r < 4; ++r){
        int n = n0 + it * 16 + q * 4 + r;
        if (n < N_NODES){
          out[(size_t)n * DMSG + col] = acc2[it][jt][r] + bb;
        }
      }
    }
  }
}

extern "C" void kernel_launch(void* const* d_in, const int* in_sizes, int n_in,
                              void* d_out, int out_size, void* d_ws, size_t ws_size,
                              hipStream_t stream){
  const float* x   = (const float*)d_in[0];
  const int*   ei  = (const int*)d_in[1];
  const float* deg = (const float*)d_in[2];
  const float* mW1 = (const float*)d_in[3];
  const float* mb1 = (const float*)d_in[4];
  const float* mW2 = (const float*)d_in[5];
  const float* mb2 = (const float*)d_in[6];
  const float* uW1 = (const float*)d_in[7];
  const float* ub1 = (const float*)d_in[8];
  const float* uW2 = (const float*)d_in[9];
  const float* ub2 = (const float*)d_in[10];

  char* ws = (char*)d_ws;
  size_t off = 0;
  float* agg = (float*)(ws + off); off += (size_t)N_NODES * DMSG * 4;        // 25.6 MB
  short* hbuf = (short*)(ws + off); off += (size_t)N_NODES * DF * 2;         // 14.4 MB
  off = (off + 255) & ~(size_t)255;
  short* w2m = (short*)(ws + off); off += (size_t)8 * 8 * 64 * 8 * 2;
  short* w1u = (short*)(ws + off); off += (size_t)9 * 16 * 64 * 8 * 2;
  short* w2u = (short*)(ws + off); off += (size_t)8 * 8 * 64 * 8 * 2;
  short* w1pq = (short*)(ws + off); off += (size_t)5 * 32 * 64 * 8 * 2;
  off = (off + 255) & ~(size_t)255;
  short* PQ = (short*)(ws + off); off += (size_t)N_NODES * PQ_LD * 2;        // 51.2 MB
  unsigned int* es = (unsigned int*)(ws + off); off += (size_t)E_EDGES * 4;  // 3.2 MB
  int* cnt    = (int*)(ws + off); off += (size_t)NSCAN * 4;
  int* offA   = (int*)(ws + off); off += (size_t)NSCAN * 4;
  int* bsum   = (int*)(ws + off); off += 256 * 4;
  int* bsumEx = (int*)(ws + off); off += 256 * 4;

  if (ws_size < off){
    sentinel_kernel<<<(N_NODES * DMSG + 255) / 256, 256, 0, stream>>>((float*)d_out);
    return;
  }

  prep_kernel<<<(N_NODES * DMSG + 255) / 256, 256, 0, stream>>>(x, deg, agg, cnt, hbuf);
  pack_hist_kernel<<<HIST_BLOCKS + PACK_THREADS / 256, 256, 0, stream>>>(
      mW1, mW2, uW1, uW2, w1pq, w2m, w1u, w2u, ei, cnt);
  scan1_kernel<<<NBLK_SCAN, 256, 0, stream>>>(cnt, offA, bsum);
  scan2_kernel<<<1, 256, 0, stream>>>(bsum, bsumEx);
  pq_scatter_kernel<<<PQ_BLOCKS + HIST_BLOCKS, 256, 0, stream>>>(
      hbuf, w1pq, mb1, PQ, ei, offA, bsumEx, es);
  edge2_kernel<<<E_EDGES / 64, 256, 0, stream>>>(PQ, es, w2m, mb2, agg);
  node_kernel<<<(N_NODES + 63) / 64, 256, 0, stream>>>(hbuf, agg, w1u, w2u, ub1, ub2,
                                                       (float*)d_out);
}